// Round 1
// baseline (84.893 us; speedup 1.0000x reference)
//
#include <hip/hip_runtime.h>

// LogSparseAttention: B=2, L=S=2048, H=8, E=D=64, fp32.
// Mask (win_len=sub_len=2048, log_l=11):
//   l < 22  : causal prefix 0..l
//   l >= 22 : {l-10..l} U {l-10-2^j >= 0, j=0..10}  (<= 22 columns)
//
// R3: 4 rows/wave, 16 lanes/row, pure-DPP reduce.
// R4: XCD-aware swizzle.            R5/R6 (reverted): bf16 / mega-buffers.
// R7: 8-wave blocks for L1 locality (~50 VGPR, 8 waves/SIMD).
// R8: HEAD-per-XCD partitioning. Old layout made each XCD's instantaneous
//     footprint the whole 512-l slab (~6.2 MB > 4 MB L2) -> L2 thrash,
//     latency-bound at ~27% of per-CU L2 BW. New layout: XCD x handles ONLY
//     head x; its entire K+V working set is one head-slice (2.0 MB) and
//     stays L2-resident for the whole kernel. Wave restructured to serve
//     one (l,h): lanes = 4 column-slots x 16 e-lanes; 22 cols -> 6 load
//     groups of 4 columns (pad slots self-invalidate: l-10-2^11 < 0).
//     Same DPP 16-lane dot-reduce; softmax/O add two __shfl_xor(16/32)
//     cross-row stages. p[] shrinks 22 -> 6 regs.

constexpr int B = 2, L = 2048, S = 2048, H = 8, E = 64;
constexpr int LOGL = 11;                 // ceil(log2(2048))
constexpr int NG   = 6;                  // 6 groups x 4 col-slots = 24 >= 22
constexpr int WPB  = 8;                  // 8 waves = 8 consecutive bl rows
constexpr int NBLK = B * L * H / WPB;    // 4096 blocks (head = blockIdx & 7)

template<int CTRL>
__device__ __forceinline__ float dpp_add(float x) {
    int y = __builtin_amdgcn_update_dpp(0, __float_as_int(x), CTRL, 0xF, 0xF, true);
    return x + __int_as_float(y);
}

__global__ __launch_bounds__(WPB * 64)
void logsparse_attn(const float4* __restrict__ Q4,
                    const float4* __restrict__ K4,
                    const float4* __restrict__ V4,
                    float4* __restrict__ O4) {
    const int h    = blockIdx.x & 7;       // head == XCD (phys blk i -> XCD i%8)
    const int n    = blockIdx.x >> 3;      // 0..511: l-group, in-order per XCD
    const int lane = threadIdx.x & 63;
    const int w    = threadIdx.x >> 6;     // wave in block: 0..7
    const int bl   = n * WPB + w;          // b*L + l, 0..4095
    const int l    = bl & (L - 1);
    const int b    = bl >> 11;             // L = 2048
    const int r    = lane >> 4;            // column slot within group: 0..3
    const int g    = lane & 15;            // float4 slot within 64-float row

    // Per-lane active column for slot i = 4*grp + r (runtime r!).
    int  cols[NG];
    bool vld[NG];
    if (l < 2 * LOGL) {                    // full causal prefix
#pragma unroll
        for (int grp = 0; grp < NG; ++grp) {
            const int i = 4 * grp + r;
            vld[grp]  = (i <= l);
            cols[grp] = vld[grp] ? i : 0;
        }
    } else {
#pragma unroll
        for (int grp = 0; grp < NG; ++grp) {
            const int i  = 4 * grp + r;
            const int e  = i - LOGL;
            const int sh = (e < 0) ? 0 : e;            // avoid UB shift
            const int c  = (e < 0) ? (l - (LOGL - 1) + i)
                                   : (l - (LOGL - 1) - (1 << sh));
            vld[grp]  = (c >= 0);          // pad slots i=22,23: 2^11,2^12 -> c<0
            cols[grp] = vld[grp] ? c : 0;
        }
    }

    const int qidx   = (bl * H + h) * (E / 4) + g;
    const int kvbase = (b * S * H + h) * (E / 4) + g;
    constexpr int CS4 = H * (E / 4);       // 128 float4 between columns

    const float4 q = Q4[qidx];             // 256 B, row-duplicated (L1 bcast)

    // Dot partials: 6 loads x (4 cols x 256 B) = 16 lines each, all L2-hot.
    float p[NG];
#pragma unroll
    for (int grp = 0; grp < NG; ++grp) {
        const float4 k = K4[kvbase + cols[grp] * CS4];
        p[grp] = fmaf(q.x, k.x, fmaf(q.y, k.y, fmaf(q.z, k.z, q.w * k.w)));
    }

    // 16-lane row sum: 4 pure-DPP stages (unchanged from R3).
#pragma unroll
    for (int grp = 0; grp < NG; ++grp) p[grp] = dpp_add<0xB1>(p[grp]);   // xor 1
#pragma unroll
    for (int grp = 0; grp < NG; ++grp) p[grp] = dpp_add<0x4E>(p[grp]);   // xor 2
#pragma unroll
    for (int grp = 0; grp < NG; ++grp) p[grp] = dpp_add<0x141>(p[grp]);  // half-mirror
#pragma unroll
    for (int grp = 0; grp < NG; ++grp) p[grp] = dpp_add<0x140>(p[grp]);  // mirror

    // Softmax across all 22 cols: local (per-slot) tree + 2 cross-row stages.
    const float scale = 0.125f;
#pragma unroll
    for (int grp = 0; grp < NG; ++grp)
        p[grp] = vld[grp] ? p[grp] * scale : -1e30f;

    float m = p[0];
#pragma unroll
    for (int grp = 1; grp < NG; ++grp) m = fmaxf(m, p[grp]);
    m = fmaxf(m, __shfl_xor(m, 16));
    m = fmaxf(m, __shfl_xor(m, 32));

    float s = 0.f;
#pragma unroll
    for (int grp = 0; grp < NG; ++grp) {
        p[grp] = __expf(p[grp] - m);       // masked: exp(-1e30 - m) -> 0
        s += p[grp];
    }
    s += __shfl_xor(s, 16);
    s += __shfl_xor(s, 32);
    const float inv = 1.0f / s;

    // O = sum_i w_i * V[col_i]; each lane covers (slot r, float4 g).
    float4 acc = make_float4(0.f, 0.f, 0.f, 0.f);
#pragma unroll
    for (int grp = 0; grp < NG; ++grp) {
        const float4 v = V4[kvbase + cols[grp] * CS4];
        acc.x = fmaf(p[grp], v.x, acc.x);
        acc.y = fmaf(p[grp], v.y, acc.y);
        acc.z = fmaf(p[grp], v.z, acc.z);
        acc.w = fmaf(p[grp], v.w, acc.w);
    }

    // Cross-row sum (rows hold disjoint column subsets of the same O[g]).
    acc.x += __shfl_xor(acc.x, 16);
    acc.y += __shfl_xor(acc.y, 16);
    acc.z += __shfl_xor(acc.z, 16);
    acc.w += __shfl_xor(acc.w, 16);
    acc.x += __shfl_xor(acc.x, 32);
    acc.y += __shfl_xor(acc.y, 32);
    acc.z += __shfl_xor(acc.z, 32);
    acc.w += __shfl_xor(acc.w, 32);

    if (r == 0)
        O4[qidx] = make_float4(acc.x * inv, acc.y * inv, acc.z * inv, acc.w * inv);
}

extern "C" void kernel_launch(void* const* d_in, const int* in_sizes, int n_in,
                              void* d_out, int out_size, void* d_ws, size_t ws_size,
                              hipStream_t stream) {
    const float4* Q = (const float4*)d_in[0];
    const float4* K = (const float4*)d_in[1];
    const float4* V = (const float4*)d_in[2];
    float4*       O = (float4*)d_out;

    logsparse_attn<<<dim3(NBLK), dim3(WPB * 64), 0, stream>>>(Q, K, V, O);
}